// Round 4
// baseline (551.621 us; speedup 1.0000x reference)
//
#include <hip/hip_runtime.h>
#include <math.h>

typedef float v2f __attribute__((ext_vector_type(2)));

namespace {

constexpr int C_DIM = 4;
constexpr int D_DIM = 64;
constexpr int H_DIM = 160;
constexpr int W_DIM = 160;

constexpr int TH = 16;
constexpr int TW = 16;
constexpr int HALO = 5;
constexpr int EH = 26;
constexpr int EW = 26;
constexpr int XST = 27;          // v2f stride of xy rows
constexpr int MST = 17;          // float4 stride of mid rows
constexpr int NPIX = EH * EW;    // 676

constexpr int TILES_W = 10;
constexpr int TPC = 100;
constexpr int NBLOCKS = 2 * C_DIM * TPC;  // 800

constexpr float C1f = 1e-4f;
constexpr float C2f = 9e-4f;
constexpr float INV_N = 1.0f / (2.0f * 64.0f * 160.0f * 160.0f);

struct GW { float g[11]; };

}  // namespace

__global__ void finalize_kernel(const float* __restrict__ partial,
                                float* __restrict__ out) {
    const int tid = threadIdx.x;
    const int c = tid >> 6;
    const int lane = tid & 63;
    float s = 0.0f;
#pragma unroll
    for (int b = 0; b < 2; ++b)
        for (int i = lane; i < TPC; i += 64)
            s += partial[b * (C_DIM * TPC) + c * TPC + i];
#pragma unroll
    for (int off = 32; off > 0; off >>= 1) s += __shfl_down(s, off, 64);
    if (lane == 0 && c < C_DIM) out[c] = 1.0f - s * INV_N;
}

__global__ __launch_bounds__(256, 4) void ssim3d_kernel(
    const float* __restrict__ img1, const float* __restrict__ img2,
    float* __restrict__ partial, GW gwp) {

    const int bid = blockIdx.x;
    const int tile = bid % TPC;
    const int c = (bid / TPC) % C_DIM;
    const int b = bid / (TPC * C_DIM);
    const int h0 = (tile / TILES_W) * TH;
    const int w0 = (tile % TILES_W) * TW;

    const long planeHW = (long)H_DIM * W_DIM;
    const long volbase = (long)(b * C_DIM + c) * D_DIM * planeHW;
    const long org = volbase + (long)(h0 - HALO) * W_DIM + (w0 - HALO);
    const float* __restrict__ p1 = img1 + org;
    const float* __restrict__ p2 = img2 + org;

    const bool interior = (h0 >= HALO) && (h0 + TH + HALO <= H_DIM) &&
                          (w0 >= HALO) && (w0 + TW + HALO <= W_DIM);

    // ---- LDS ----
    __shared__ v2f    xy[2][EH][XST];   // interleaved (x,y), b64 access
    __shared__ float4 mid[EH][MST];     // W-conv (sx,sy | sq,sp), b128 access
    __shared__ float  rbuf[4];

    const int tid = threadIdx.x;

    // ---- staging decode (3 positions/thread) ----
    int hh_[3], ww_[3], off_[3];
    bool live_[3], ok_[3];
#pragma unroll
    for (int k = 0; k < 3; ++k) {
        const int e = tid + k * 256;
        live_[k] = (e < NPIX);
        const int hh = e / EW;
        const int ww = e - hh * EW;
        hh_[k] = hh; ww_[k] = ww;
        off_[k] = hh * W_DIM + ww;
        const int gh = h0 - HALO + hh;
        const int gw = w0 - HALO + ww;
        ok_[k] = ((unsigned)gh < (unsigned)H_DIM) &&
                 ((unsigned)gw < (unsigned)W_DIM);
    }

    auto fetch_slice = [&](int s, v2f lv[3]) {
        const long sb = (long)s * planeHW;
#pragma unroll
        for (int k = 0; k < 3; ++k) {
            lv[k] = (v2f){0.0f, 0.0f};
            if (live_[k] && (interior || ok_[k])) {
                const long gi = sb + off_[k];
                lv[k].x = p1[gi];
                lv[k].y = p2[gi];
            }
        }
    };
    auto commit_slice = [&](int buf, const v2f lv[3]) {
#pragma unroll
        for (int k = 0; k < 3; ++k)
            if (live_[k]) xy[buf][hh_[k]][ww_[k]] = lv[k];
    };

    // ---- wconv: 208 workers (hh fastest), 2 outputs each, streaming window
    const bool wactive = (tid < 208);
    const int whh = tid % 26;
    const int wwg = (tid / 26) * 2;   // 0,2,..,14

    auto wconv = [&](int cur) {
        v2f a0 = {0.f, 0.f}, b0 = {0.f, 0.f};
        v2f a1 = {0.f, 0.f}, b1 = {0.f, 0.f};
#pragma unroll
        for (int t = 0; t < 12; ++t) {
            const v2f xv = xy[cur][whh][wwg + t];
            const v2f sq = xv * xv;
            v2f qp;
            qp.x = sq.x + sq.y;      // x^2 + y^2
            qp.y = xv.x * xv.y;      // x*y
            if (t < 11) {
                const v2f g2 = {gwp.g[t], gwp.g[t]};
                a0 = __builtin_elementwise_fma(g2, xv, a0);
                b0 = __builtin_elementwise_fma(g2, qp, b0);
            }
            if (t >= 1) {
                const v2f g2 = {gwp.g[t - 1], gwp.g[t - 1]};
                a1 = __builtin_elementwise_fma(g2, xv, a1);
                b1 = __builtin_elementwise_fma(g2, qp, b1);
            }
        }
        mid[whh][wwg]     = make_float4(a0.x, a0.y, b0.x, b0.y);
        mid[whh][wwg + 1] = make_float4(a1.x, a1.y, b1.x, b1.y);
    };

    // ---- per-pixel state: transposed-FIR ring along D ----
    const int h_out = tid >> 4;
    const int w_out = tid & 15;
    v2f rxy[11], rqp[11];
#pragma unroll
    for (int i = 0; i < 11; ++i) {
        rxy[i] = (v2f){0.f, 0.f};
        rqp[i] = (v2f){0.f, 0.f};
    }
    float accum = 0.0f;

    auto consume = [&](int slot) {
        const float m1 = rxy[slot].x, m2 = rxy[slot].y;
        const float q = rqp[slot].x, pp = rqp[slot].y;
        const float m1s = m1 * m1;
        const float m2s = m2 * m2;
        const float m12 = m1 * m2;
        const float spp = q - m1s - m2s;
        const float s12 = pp - m12;
        const float num = (2.0f * m12 + C1f) * (2.0f * s12 + C2f);
        const float den = (m1s + m2s + C1f) * (spp + C2f);
        accum = fmaf(num, __builtin_amdgcn_rcpf(den), accum);
    };

    // preload slice 0 -> buf 0
    {
        v2f lv[3];
        fetch_slice(0, lv);
        commit_slice(0, lv);
    }
    __syncthreads();

    // main loop: s = s0+p, s0 multiple of 11 -> all ring indices static
    for (int s0 = 0; s0 < 66; s0 += 11) {
#pragma unroll
        for (int p = 0; p < 11; ++p) {
            const int s = s0 + p;
            const bool compute = (s < D_DIM);
            const bool have_next = (s + 1 < D_DIM);
            v2f lv[3];
            if (compute) {
                if (have_next) fetch_slice(s + 1, lv);
                if (wactive) wconv(s & 1);
                if (have_next) commit_slice((s + 1) & 1, lv);
            }
            __syncthreads();
            if (compute) {
                // H-conv for this pixel, packed
                v2f zxy = {0.f, 0.f}, zqp = {0.f, 0.f};
#pragma unroll
                for (int t = 0; t < 11; ++t) {
                    const float4 m = mid[h_out + t][w_out];
                    const v2f g2 = {gwp.g[t], gwp.g[t]};
                    const v2f ma = {m.x, m.y};
                    const v2f mb = {m.z, m.w};
                    zxy = __builtin_elementwise_fma(g2, ma, zxy);
                    zqp = __builtin_elementwise_fma(g2, mb, zqp);
                }
                // scatter into ring: output d = s+5-t, slot = d mod 11.
                // t==0 assigns (first touch of output s+5) -> clears stale
                // prologue garbage; t>0 accumulates.
#pragma unroll
                for (int t = 0; t < 11; ++t) {
                    const int slot = (p + 16 - t) % 11;
                    const v2f g2 = {gwp.g[t], gwp.g[t]};
                    if (t == 0) {
                        rxy[slot] = g2 * zxy;
                        rqp[slot] = g2 * zqp;
                    } else {
                        rxy[slot] = __builtin_elementwise_fma(g2, zxy, rxy[slot]);
                        rqp[slot] = __builtin_elementwise_fma(g2, zqp, rqp[slot]);
                    }
                }
            }
            if (s >= HALO) consume((p + 6) % 11);  // output d = s-5
            __syncthreads();
        }
    }
    // epilogue: s = 66,67,68 -> outputs 61,62,63, slots 6,7,8
    consume(6);
    consume(7);
    consume(8);

    // ---- block reduction -> one partial per block ----
#pragma unroll
    for (int off = 32; off > 0; off >>= 1) accum += __shfl_down(accum, off, 64);
    const int wave = tid >> 6;
    const int lane = tid & 63;
    if (lane == 0) rbuf[wave] = accum;
    __syncthreads();
    if (tid == 0) partial[bid] = rbuf[0] + rbuf[1] + rbuf[2] + rbuf[3];
}

extern "C" void kernel_launch(void* const* d_in, const int* in_sizes, int n_in,
                              void* d_out, int out_size, void* d_ws, size_t ws_size,
                              hipStream_t stream) {
    const float* img1 = (const float*)d_in[0];
    const float* img2 = (const float*)d_in[1];
    float* out = (float*)d_out;
    float* partial = (float*)d_ws;

    GW gw;
    {
        double gd[11];
        double ssum = 0.0;
        for (int i = 0; i < 11; ++i) {
            const double t = (double)(i - 5);
            gd[i] = exp(-(t * t) / 4.5);
            ssum += gd[i];
        }
        for (int i = 0; i < 11; ++i) gw.g[i] = (float)(gd[i] / ssum);
    }

    ssim3d_kernel<<<NBLOCKS, 256, 0, stream>>>(img1, img2, partial, gw);
    finalize_kernel<<<1, 256, 0, stream>>>(partial, out);
}

// Round 5
// 230.177 us; speedup vs baseline: 2.3965x; 2.3965x over previous
//
#include <hip/hip_runtime.h>
#include <math.h>

typedef float v2f __attribute__((ext_vector_type(2)));

namespace {

constexpr int C_DIM = 4;
constexpr int D_DIM = 64;
constexpr int H_DIM = 160;
constexpr int W_DIM = 160;

constexpr int TH = 16;
constexpr int TW = 16;
constexpr int HALO = 5;
constexpr int EH = 26;
constexpr int EW = 26;
constexpr int XST = 27;          // v2f stride of xy rows
constexpr int MST = 17;          // float4 stride of mid rows
constexpr int NPIX = EH * EW;    // 676

constexpr int TILES_W = 10;
constexpr int TPC = 100;
constexpr int NBLOCKS = 2 * C_DIM * TPC;  // 800

constexpr float C1f = 1e-4f;
constexpr float C2f = 9e-4f;
constexpr float INV_N = 1.0f / (2.0f * 64.0f * 160.0f * 160.0f);

struct GW { float g[11]; };

}  // namespace

__global__ void finalize_kernel(const float* __restrict__ partial,
                                float* __restrict__ out) {
    const int tid = threadIdx.x;
    const int c = tid >> 6;
    const int lane = tid & 63;
    float s = 0.0f;
#pragma unroll
    for (int b = 0; b < 2; ++b)
        for (int i = lane; i < TPC; i += 64)
            s += partial[b * (C_DIM * TPC) + c * TPC + i];
#pragma unroll
    for (int off = 32; off > 0; off >>= 1) s += __shfl_down(s, off, 64);
    if (lane == 0 && c < C_DIM) out[c] = 1.0f - s * INV_N;
}

__global__ __launch_bounds__(256, 4) void ssim3d_kernel(
    const float* __restrict__ img1, const float* __restrict__ img2,
    float* __restrict__ partial, GW gwp) {

    const int bid = blockIdx.x;
    const int tile = bid % TPC;
    const int c = (bid / TPC) % C_DIM;
    const int b = bid / (TPC * C_DIM);
    const int h0 = (tile / TILES_W) * TH;
    const int w0 = (tile % TILES_W) * TW;

    const long planeHW = (long)H_DIM * W_DIM;
    const long volbase = (long)(b * C_DIM + c) * D_DIM * planeHW;
    const long org = volbase + (long)(h0 - HALO) * W_DIM + (w0 - HALO);
    const float* __restrict__ p1 = img1 + org;
    const float* __restrict__ p2 = img2 + org;

    const bool interior = (h0 >= HALO) && (h0 + TH + HALO <= H_DIM) &&
                          (w0 >= HALO) && (w0 + TW + HALO <= W_DIM);

    // ---- LDS ----
    __shared__ v2f    xy[2][EH][XST];   // interleaved (x,y), b64 access
    __shared__ float4 mid[EH][MST];     // W-conv (sx,sy | sq,sp), b128 access
    __shared__ float  rbuf[4];

    const int tid = threadIdx.x;

    // ---- staging decode (3 positions/thread) ----
    int hh_[3], ww_[3], off_[3];
    bool live_[3], ok_[3];
#pragma unroll
    for (int k = 0; k < 3; ++k) {
        const int e = tid + k * 256;
        live_[k] = (e < NPIX);
        const int hh = e / EW;
        const int ww = e - hh * EW;
        hh_[k] = hh; ww_[k] = ww;
        off_[k] = hh * W_DIM + ww;
        const int gh = h0 - HALO + hh;
        const int gw = w0 - HALO + ww;
        ok_[k] = ((unsigned)gh < (unsigned)H_DIM) &&
                 ((unsigned)gw < (unsigned)W_DIM);
    }

    auto fetch_slice = [&](int s, v2f lv[3]) {
        const long sb = (long)s * planeHW;
#pragma unroll
        for (int k = 0; k < 3; ++k) {
            lv[k] = (v2f){0.0f, 0.0f};
            if (live_[k] && (interior || ok_[k])) {
                const long gi = sb + off_[k];
                lv[k].x = p1[gi];
                lv[k].y = p2[gi];
            }
        }
    };
    auto commit_slice = [&](int buf, const v2f lv[3]) {
#pragma unroll
        for (int k = 0; k < 3; ++k)
            if (live_[k]) xy[buf][hh_[k]][ww_[k]] = lv[k];
    };

    // ---- wconv: 208 workers (hh fastest), 2 outputs each, streaming window
    const bool wactive = (tid < 208);
    const int whh = tid % 26;
    const int wwg = (tid / 26) * 2;   // 0,2,..,14

    auto wconv = [&](int cur) {
        v2f a0 = {0.f, 0.f}, b0 = {0.f, 0.f};
        v2f a1 = {0.f, 0.f}, b1 = {0.f, 0.f};
#pragma unroll
        for (int t = 0; t < 12; ++t) {
            const v2f xv = xy[cur][whh][wwg + t];
            const v2f sq = xv * xv;
            v2f qp;
            qp.x = sq.x + sq.y;      // x^2 + y^2
            qp.y = xv.x * xv.y;      // x*y
            if (t < 11) {
                const v2f g2 = {gwp.g[t], gwp.g[t]};
                a0 = __builtin_elementwise_fma(g2, xv, a0);
                b0 = __builtin_elementwise_fma(g2, qp, b0);
            }
            if (t >= 1) {
                const v2f g2 = {gwp.g[t - 1], gwp.g[t - 1]};
                a1 = __builtin_elementwise_fma(g2, xv, a1);
                b1 = __builtin_elementwise_fma(g2, qp, b1);
            }
        }
        mid[whh][wwg]     = make_float4(a0.x, a0.y, b0.x, b0.y);
        mid[whh][wwg + 1] = make_float4(a1.x, a1.y, b1.x, b1.y);
    };

    // ---- per-pixel D sliding window: 22 v2f, shift-based, static indices only
    const int h_out = tid >> 4;
    const int w_out = tid & 15;
    v2f wxy[11], wqp[11];
#pragma unroll
    for (int i = 0; i < 11; ++i) {
        wxy[i] = (v2f){0.f, 0.f};
        wqp[i] = (v2f){0.f, 0.f};
    }
    float accum = 0.0f;

    // H-conv at this thread's (h,w), packed
    auto hconv = [&](v2f& zxy, v2f& zqp) {
        zxy = (v2f){0.f, 0.f};
        zqp = (v2f){0.f, 0.f};
#pragma unroll
        for (int t = 0; t < 11; ++t) {
            const float4 m = mid[h_out + t][w_out];
            const v2f g2 = {gwp.g[t], gwp.g[t]};
            const v2f ma = {m.x, m.y};
            const v2f mb = {m.z, m.w};
            zxy = __builtin_elementwise_fma(g2, ma, zxy);
            zqp = __builtin_elementwise_fma(g2, mb, zqp);
        }
    };

    auto shift_insert = [&](v2f zxy, v2f zqp) {
#pragma unroll
        for (int i = 0; i < 10; ++i) {
            wxy[i] = wxy[i + 1];
            wqp[i] = wqp[i + 1];
        }
        wxy[10] = zxy;
        wqp[10] = zqp;
    };

    // D-conv over window + SSIM; window holds slices s-10..s, output d=s-5
    auto consume = [&]() {
        v2f mxy = {0.f, 0.f}, mqp = {0.f, 0.f};
#pragma unroll
        for (int t = 0; t < 11; ++t) {
            const v2f g2 = {gwp.g[t], gwp.g[t]};
            mxy = __builtin_elementwise_fma(g2, wxy[t], mxy);
            mqp = __builtin_elementwise_fma(g2, wqp[t], mqp);
        }
        const float m1 = mxy.x, m2 = mxy.y;
        const float q = mqp.x, pp = mqp.y;
        const float m1s = m1 * m1;
        const float m2s = m2 * m2;
        const float m12 = m1 * m2;
        const float spp = q - m1s - m2s;   // sigma1^2 + sigma2^2
        const float s12 = pp - m12;        // sigma12
        const float num = (2.0f * m12 + C1f) * (2.0f * s12 + C2f);
        const float den = (m1s + m2s + C1f) * (spp + C2f);
        accum = fmaf(num, __builtin_amdgcn_rcpf(den), accum);
    };

    // preload slice 0 -> buf 0
    {
        v2f lv[3];
        fetch_slice(0, lv);
        commit_slice(0, lv);
    }
    __syncthreads();

    for (int s = 0; s < D_DIM; ++s) {
        const int cur = s & 1;
        // Phase A: issue next-slice loads, W-conv current, commit next slice
        v2f lv[3];
        const bool have_next = (s + 1 < D_DIM);
        if (have_next) fetch_slice(s + 1, lv);
        if (wactive) wconv(cur);
        if (have_next) commit_slice(cur ^ 1, lv);
        __syncthreads();
        // Phase B: H-conv, D-window update, consume
        v2f zxy, zqp;
        hconv(zxy, zqp);
        shift_insert(zxy, zqp);
        if (s >= HALO) consume();
        __syncthreads();
    }
    // D tail: zero padding slices
#pragma unroll
    for (int s = D_DIM; s < D_DIM + HALO; ++s) {
        shift_insert((v2f){0.f, 0.f}, (v2f){0.f, 0.f});
        consume();
    }

    // ---- block reduction -> one partial per block ----
#pragma unroll
    for (int off = 32; off > 0; off >>= 1) accum += __shfl_down(accum, off, 64);
    const int wave = tid >> 6;
    const int lane = tid & 63;
    if (lane == 0) rbuf[wave] = accum;
    __syncthreads();
    if (tid == 0) partial[bid] = rbuf[0] + rbuf[1] + rbuf[2] + rbuf[3];
}

extern "C" void kernel_launch(void* const* d_in, const int* in_sizes, int n_in,
                              void* d_out, int out_size, void* d_ws, size_t ws_size,
                              hipStream_t stream) {
    const float* img1 = (const float*)d_in[0];
    const float* img2 = (const float*)d_in[1];
    float* out = (float*)d_out;
    float* partial = (float*)d_ws;

    GW gw;
    {
        double gd[11];
        double ssum = 0.0;
        for (int i = 0; i < 11; ++i) {
            const double t = (double)(i - 5);
            gd[i] = exp(-(t * t) / 4.5);
            ssum += gd[i];
        }
        for (int i = 0; i < 11; ++i) gw.g[i] = (float)(gd[i] / ssum);
    }

    ssim3d_kernel<<<NBLOCKS, 256, 0, stream>>>(img1, img2, partial, gw);
    finalize_kernel<<<1, 256, 0, stream>>>(partial, out);
}

// Round 6
// 216.078 us; speedup vs baseline: 2.5529x; 1.0652x over previous
//
#include <hip/hip_runtime.h>
#include <math.h>

typedef float v2f __attribute__((ext_vector_type(2)));

namespace {

constexpr int C_DIM = 4;
constexpr int D_DIM = 64;
constexpr int H_DIM = 160;
constexpr int W_DIM = 160;

constexpr int TH = 16;
constexpr int TW = 16;
constexpr int HALO = 5;
constexpr int EH = 26;
constexpr int EW = 26;
constexpr int XST = 27;          // v2f stride of xy rows
constexpr int MST = 17;          // float4 stride of mid rows
constexpr int NPIX = EH * EW;    // 676

constexpr int TILES_W = 10;
constexpr int TPC = 100;
constexpr int NBLOCKS = 2 * C_DIM * TPC;  // 800

constexpr float C1f = 1e-4f;
constexpr float C2f = 9e-4f;
constexpr float INV_N = 1.0f / (2.0f * 64.0f * 160.0f * 160.0f);

struct GW { float g[11]; };

}  // namespace

__global__ void finalize_kernel(const float* __restrict__ partial,
                                float* __restrict__ out) {
    const int tid = threadIdx.x;
    const int c = tid >> 6;
    const int lane = tid & 63;
    float s = 0.0f;
#pragma unroll
    for (int b = 0; b < 2; ++b)
        for (int i = lane; i < TPC; i += 64)
            s += partial[b * (C_DIM * TPC) + c * TPC + i];
#pragma unroll
    for (int off = 32; off > 0; off >>= 1) s += __shfl_down(s, off, 64);
    if (lane == 0 && c < C_DIM) out[c] = 1.0f - s * INV_N;
}

__global__ __launch_bounds__(256, 4) void ssim3d_kernel(
    const float* __restrict__ img1, const float* __restrict__ img2,
    float* __restrict__ partial, GW gwp) {

    const int bid = blockIdx.x;
    const int tile = bid % TPC;
    const int c = (bid / TPC) % C_DIM;
    const int b = bid / (TPC * C_DIM);
    const int h0 = (tile / TILES_W) * TH;
    const int w0 = (tile % TILES_W) * TW;

    const long planeHW = (long)H_DIM * W_DIM;
    const long volbase = (long)(b * C_DIM + c) * D_DIM * planeHW;
    const long org = volbase + (long)(h0 - HALO) * W_DIM + (w0 - HALO);
    const float* __restrict__ p1 = img1 + org;
    const float* __restrict__ p2 = img2 + org;

    const bool interior = (h0 >= HALO) && (h0 + TH + HALO <= H_DIM) &&
                          (w0 >= HALO) && (w0 + TW + HALO <= W_DIM);

    // ---- LDS (both stages double-buffered -> 1 barrier per slice) ----
    __shared__ v2f    xy[2][EH][XST];    // interleaved (x,y), b64 access
    __shared__ float4 mid[2][EH][MST];   // W-conv (sx,sy | sq,sp), b128
    __shared__ float  rbuf[4];

    const int tid = threadIdx.x;

    // ---- staging decode (3 positions/thread) ----
    int hh_[3], ww_[3], off_[3];
    bool live_[3], ok_[3];
#pragma unroll
    for (int k = 0; k < 3; ++k) {
        const int e = tid + k * 256;
        live_[k] = (e < NPIX);
        const int hh = e / EW;
        const int ww = e - hh * EW;
        hh_[k] = hh; ww_[k] = ww;
        off_[k] = hh * W_DIM + ww;
        const int gh = h0 - HALO + hh;
        const int gw = w0 - HALO + ww;
        ok_[k] = ((unsigned)gh < (unsigned)H_DIM) &&
                 ((unsigned)gw < (unsigned)W_DIM);
    }

    auto fetch_slice = [&](int s, v2f lv[3]) {
        const long sb = (long)s * planeHW;
#pragma unroll
        for (int k = 0; k < 3; ++k) {
            lv[k] = (v2f){0.0f, 0.0f};
            if (live_[k] && (interior || ok_[k])) {
                const long gi = sb + off_[k];
                lv[k].x = p1[gi];
                lv[k].y = p2[gi];
            }
        }
    };
    auto commit_slice = [&](int buf, const v2f lv[3]) {
#pragma unroll
        for (int k = 0; k < 3; ++k)
            if (live_[k]) xy[buf][hh_[k]][ww_[k]] = lv[k];
    };

    // ---- wconv: 208 workers (hh fastest), 2 outputs each, streaming window
    const bool wactive = (tid < 208);
    const int whh = tid % 26;
    const int wwg = (tid / 26) * 2;   // 0,2,..,14

    auto wconv = [&](int cur) {
        v2f a0 = {0.f, 0.f}, b0 = {0.f, 0.f};
        v2f a1 = {0.f, 0.f}, b1 = {0.f, 0.f};
#pragma unroll
        for (int t = 0; t < 12; ++t) {
            const v2f xv = xy[cur][whh][wwg + t];
            const v2f sq = xv * xv;
            v2f qp;
            qp.x = sq.x + sq.y;      // x^2 + y^2
            qp.y = xv.x * xv.y;      // x*y
            if (t < 11) {
                const v2f g2 = {gwp.g[t], gwp.g[t]};
                a0 = __builtin_elementwise_fma(g2, xv, a0);
                b0 = __builtin_elementwise_fma(g2, qp, b0);
            }
            if (t >= 1) {
                const v2f g2 = {gwp.g[t - 1], gwp.g[t - 1]};
                a1 = __builtin_elementwise_fma(g2, xv, a1);
                b1 = __builtin_elementwise_fma(g2, qp, b1);
            }
        }
        mid[cur][whh][wwg]     = make_float4(a0.x, a0.y, b0.x, b0.y);
        mid[cur][whh][wwg + 1] = make_float4(a1.x, a1.y, b1.x, b1.y);
    };

    // H-conv at this thread's (h,w), packed
    const int h_out = tid >> 4;
    const int w_out = tid & 15;
    auto hconv = [&](int cur, v2f& zxy, v2f& zqp) {
        zxy = (v2f){0.f, 0.f};
        zqp = (v2f){0.f, 0.f};
#pragma unroll
        for (int t = 0; t < 11; ++t) {
            const float4 m = mid[cur][h_out + t][w_out];
            const v2f g2 = {gwp.g[t], gwp.g[t]};
            const v2f ma = {m.x, m.y};
            const v2f mb = {m.z, m.w};
            zxy = __builtin_elementwise_fma(g2, ma, zxy);
            zqp = __builtin_elementwise_fma(g2, mb, zqp);
        }
    };

    float accum = 0.0f;
    // SSIM from D-convolved values (by value -- no register-array indices)
    auto ssim_add = [&](v2f mxy, v2f mqp) {
        const float m1 = mxy.x, m2 = mxy.y;
        const float q = mqp.x, pp = mqp.y;
        const float m1s = m1 * m1;
        const float m2s = m2 * m2;
        const float m12 = m1 * m2;
        const float spp = q - m1s - m2s;   // sigma1^2 + sigma2^2
        const float s12 = pp - m12;        // sigma12
        const float num = (2.0f * m12 + C1f) * (2.0f * s12 + C2f);
        const float den = (m1s + m2s + C1f) * (spp + C2f);
        accum = fmaf(num, __builtin_amdgcn_rcpf(den), accum);
    };

    // ---- D window: 14 slots, insert at 10+u, consume over [u..u+10],
    // shift by 4 once per 4 slices. Static indices only (SROA-safe).
    v2f wxy[14], wqp[14];
#pragma unroll
    for (int i = 0; i < 14; ++i) {
        wxy[i] = (v2f){0.f, 0.f};
        wqp[i] = (v2f){0.f, 0.f};
    }

    // prologue: slice 0 -> xy[0]
    {
        v2f lv[3];
        fetch_slice(0, lv);
        commit_slice(0, lv);
    }
    __syncthreads();

    for (int sb = 0; sb < D_DIM; sb += 4) {   // sb even -> s&1 == u&1 (static)
#pragma unroll
        for (int u = 0; u < 4; ++u) {
            const int s = sb + u;
            v2f lv[3];
            const bool have_next = (s + 1 < D_DIM);
            if (have_next) fetch_slice(s + 1, lv);
            if (wactive) wconv(u & 1);
            if (have_next) commit_slice((u + 1) & 1, lv);
            __syncthreads();
            v2f zxy, zqp;
            hconv(u & 1, zxy, zqp);
            wxy[10 + u] = zxy;
            wqp[10 + u] = zqp;
            if (s >= HALO) {   // output d = s-5, taps over wN[u..u+10]
                v2f mxy = {0.f, 0.f}, mqp = {0.f, 0.f};
#pragma unroll
                for (int t = 0; t < 11; ++t) {
                    const v2f g2 = {gwp.g[t], gwp.g[t]};
                    mxy = __builtin_elementwise_fma(g2, wxy[u + t], mxy);
                    mqp = __builtin_elementwise_fma(g2, wqp[u + t], mqp);
                }
                ssim_add(mxy, mqp);
            }
        }
        // shift window by 4
#pragma unroll
        for (int k = 0; k < 10; ++k) {
            wxy[k] = wxy[k + 4];
            wqp[k] = wqp[k + 4];
        }
    }

    // epilogue: outputs 59..63. Window now holds slices 54+k at wN[k],
    // k=0..9; slices >= 64 are zero padding.
#pragma unroll
    for (int i = 10; i < 14; ++i) {
        wxy[i] = (v2f){0.f, 0.f};
        wqp[i] = (v2f){0.f, 0.f};
    }
#pragma unroll
    for (int u2 = 0; u2 < 5; ++u2) {   // output d = 59 + u2
        v2f mxy = {0.f, 0.f}, mqp = {0.f, 0.f};
#pragma unroll
        for (int t = 0; t < 11; ++t) {
            if (u2 + t <= 13) {        // static guard; dropped taps are zero
                const v2f g2 = {gwp.g[t], gwp.g[t]};
                mxy = __builtin_elementwise_fma(g2, wxy[u2 + t], mxy);
                mqp = __builtin_elementwise_fma(g2, wqp[u2 + t], mqp);
            }
        }
        ssim_add(mxy, mqp);
    }

    // ---- block reduction -> one partial per block ----
#pragma unroll
    for (int off = 32; off > 0; off >>= 1) accum += __shfl_down(accum, off, 64);
    const int wave = tid >> 6;
    const int lane = tid & 63;
    if (lane == 0) rbuf[wave] = accum;
    __syncthreads();
    if (tid == 0) partial[bid] = rbuf[0] + rbuf[1] + rbuf[2] + rbuf[3];
}

extern "C" void kernel_launch(void* const* d_in, const int* in_sizes, int n_in,
                              void* d_out, int out_size, void* d_ws, size_t ws_size,
                              hipStream_t stream) {
    const float* img1 = (const float*)d_in[0];
    const float* img2 = (const float*)d_in[1];
    float* out = (float*)d_out;
    float* partial = (float*)d_ws;

    GW gw;
    {
        double gd[11];
        double ssum = 0.0;
        for (int i = 0; i < 11; ++i) {
            const double t = (double)(i - 5);
            gd[i] = exp(-(t * t) / 4.5);
            ssum += gd[i];
        }
        for (int i = 0; i < 11; ++i) gw.g[i] = (float)(gd[i] / ssum);
    }

    ssim3d_kernel<<<NBLOCKS, 256, 0, stream>>>(img1, img2, partial, gw);
    finalize_kernel<<<1, 256, 0, stream>>>(partial, out);
}

// Round 7
// 208.003 us; speedup vs baseline: 2.6520x; 1.0388x over previous
//
#include <hip/hip_runtime.h>
#include <math.h>

typedef float v2f __attribute__((ext_vector_type(2)));

namespace {

constexpr int C_DIM = 4;
constexpr int D_DIM = 64;
constexpr int H_DIM = 160;
constexpr int W_DIM = 160;

constexpr int TH = 20;
constexpr int TW = 20;
constexpr int HALO = 5;
constexpr int EH = 30;
constexpr int EW = 30;
constexpr int XST = 31;          // v2f stride of xy rows (odd)
constexpr int MST = 21;          // float4 stride of mid rows (odd)
constexpr int NPIX = EH * EW;    // 900

constexpr int TILES_W = 8;       // 160/20
constexpr int TPC = 64;          // 8x8 tiles per (b,c)
constexpr int NBLOCKS = 2 * C_DIM * TPC;  // 512 = exactly 2 blocks/CU

constexpr float C1f = 1e-4f;
constexpr float C2f = 9e-4f;
constexpr float INV_N = 1.0f / (2.0f * 64.0f * 160.0f * 160.0f);

struct GW { float g[11]; };

}  // namespace

__global__ void finalize_kernel(const float* __restrict__ partial,
                                float* __restrict__ out) {
    const int tid = threadIdx.x;
    const int c = tid >> 6;        // one wave per channel
    const int lane = tid & 63;     // lane == tile index (TPC == 64)
    float s = partial[c * TPC + lane] +
              partial[C_DIM * TPC + c * TPC + lane];
#pragma unroll
    for (int off = 32; off > 0; off >>= 1) s += __shfl_down(s, off, 64);
    if (lane == 0 && c < C_DIM) out[c] = 1.0f - s * INV_N;
}

__global__ __launch_bounds__(256, 2) void ssim3d_kernel(
    const float* __restrict__ img1, const float* __restrict__ img2,
    float* __restrict__ partial, GW gwp) {

    const int bid = blockIdx.x;
    const int tile = bid % TPC;
    const int c = (bid / TPC) % C_DIM;
    const int b = bid / (TPC * C_DIM);
    const int h0 = (tile / TILES_W) * TH;
    const int w0 = (tile % TILES_W) * TW;

    const long planeHW = (long)H_DIM * W_DIM;
    const long volbase = (long)(b * C_DIM + c) * D_DIM * planeHW;
    const long org = volbase + (long)(h0 - HALO) * W_DIM + (w0 - HALO);
    const float* __restrict__ p1 = img1 + org;
    const float* __restrict__ p2 = img2 + org;

    const bool interior = (h0 >= HALO) && (h0 + TH + HALO <= H_DIM) &&
                          (w0 >= HALO) && (w0 + TW + HALO <= W_DIM);

    // ---- LDS (both stages double-buffered -> 1 barrier per slice) ----
    __shared__ v2f    xy[2][EH][XST];    // interleaved (x,y), b64
    __shared__ float4 mid[2][EH][MST];   // W-conv (sx,sy | sq,sp), b128
    __shared__ float  rbuf[4];

    const int tid = threadIdx.x;

    // ---- staging decode (4 positions/thread, 900 px) ----
    int hh_[4], ww_[4], off_[4];
    bool live_[4], ok_[4];
#pragma unroll
    for (int k = 0; k < 4; ++k) {
        const int e = tid + k * 256;
        live_[k] = (e < NPIX);
        const int hh = e / EW;
        const int ww = e - hh * EW;
        hh_[k] = hh; ww_[k] = ww;
        off_[k] = hh * W_DIM + ww;
        const int gh = h0 - HALO + hh;
        const int gw = w0 - HALO + ww;
        ok_[k] = ((unsigned)gh < (unsigned)H_DIM) &&
                 ((unsigned)gw < (unsigned)W_DIM);
    }

    auto fetch_slice = [&](int s, v2f lv[4]) {
        const long sb = (long)s * planeHW;
#pragma unroll
        for (int k = 0; k < 4; ++k) {
            lv[k] = (v2f){0.0f, 0.0f};
            if (live_[k] && (interior || ok_[k])) {
                const long gi = sb + off_[k];
                lv[k].x = p1[gi];
                lv[k].y = p2[gi];
            }
        }
    };
    auto commit_slice = [&](int buf, const v2f lv[4]) {
#pragma unroll
        for (int k = 0; k < 4; ++k)
            if (live_[k]) xy[buf][hh_[k]][ww_[k]] = lv[k];
    };

    // ---- wconv: 150 workers (rows fastest), 4 outputs each, 14-tap stream
    const bool wactive = (tid < 150);
    const int whh = tid % 30;
    const int wg  = (tid / 30) * 4;   // 0,4,8,12,16

    auto wconv = [&](int cur) {
        v2f a0 = {0.f,0.f}, a1 = {0.f,0.f}, a2 = {0.f,0.f}, a3 = {0.f,0.f};
        v2f q0 = {0.f,0.f}, q1 = {0.f,0.f}, q2 = {0.f,0.f}, q3 = {0.f,0.f};
#pragma unroll
        for (int t = 0; t < 14; ++t) {
            const v2f xv = xy[cur][whh][wg + t];
            v2f qp;
            qp.x = fmaf(xv.x, xv.x, xv.y * xv.y);  // x^2 + y^2
            qp.y = xv.x * xv.y;                    // x*y
            if (t <= 10) {
                const v2f g2 = {gwp.g[t], gwp.g[t]};
                a0 = __builtin_elementwise_fma(g2, xv, a0);
                q0 = __builtin_elementwise_fma(g2, qp, q0);
            }
            if (t >= 1 && t <= 11) {
                const v2f g2 = {gwp.g[t-1], gwp.g[t-1]};
                a1 = __builtin_elementwise_fma(g2, xv, a1);
                q1 = __builtin_elementwise_fma(g2, qp, q1);
            }
            if (t >= 2 && t <= 12) {
                const v2f g2 = {gwp.g[t-2], gwp.g[t-2]};
                a2 = __builtin_elementwise_fma(g2, xv, a2);
                q2 = __builtin_elementwise_fma(g2, qp, q2);
            }
            if (t >= 3) {
                const v2f g2 = {gwp.g[t-3], gwp.g[t-3]};
                a3 = __builtin_elementwise_fma(g2, xv, a3);
                q3 = __builtin_elementwise_fma(g2, qp, q3);
            }
        }
        mid[cur][whh][wg]     = make_float4(a0.x, a0.y, q0.x, q0.y);
        mid[cur][whh][wg + 1] = make_float4(a1.x, a1.y, q1.x, q1.y);
        mid[cur][whh][wg + 2] = make_float4(a2.x, a2.y, q2.x, q2.y);
        mid[cur][whh][wg + 3] = make_float4(a3.x, a3.y, q3.x, q3.y);
    };

    // ---- hconv: 200 workers, 2 H-outputs each (rows h, h+1), 12-tap stream
    const bool hworker = (tid < 200);
    const int hw = tid % 20;          // w position
    const int hb = (tid / 20) * 2;    // h base: 0,2,..,18

    float accum = 0.0f;
    auto ssim_add = [&](v2f mxy, v2f mqp) {
        const float m1 = mxy.x, m2 = mxy.y;
        const float q = mqp.x, pp = mqp.y;
        const float m1s = m1 * m1;
        const float m2s = m2 * m2;
        const float m12 = m1 * m2;
        const float spp = q - m1s - m2s;
        const float s12 = pp - m12;
        const float num = (2.0f * m12 + C1f) * (2.0f * s12 + C2f);
        const float den = (m1s + m2s + C1f) * (spp + C2f);
        accum = fmaf(num, __builtin_amdgcn_rcpf(den), accum);
    };

    // two D-windows (outputs h=hb and h=hb+1): 14 slots, insert at 10+u,
    // consume over [u..u+10], shift by 4 per 4 slices. Static indices only.
    v2f w0xy[14], w0qp[14], w1xy[14], w1qp[14];
#pragma unroll
    for (int i = 0; i < 14; ++i) {
        w0xy[i] = (v2f){0.f, 0.f}; w0qp[i] = (v2f){0.f, 0.f};
        w1xy[i] = (v2f){0.f, 0.f}; w1qp[i] = (v2f){0.f, 0.f};
    }

    // prologue: slice 0 -> xy[0]
    {
        v2f lv[4];
        fetch_slice(0, lv);
        commit_slice(0, lv);
    }
    __syncthreads();

    for (int sb = 0; sb < D_DIM; sb += 4) {   // sb multiple of 4 -> s&1 == u&1
#pragma unroll
        for (int u = 0; u < 4; ++u) {
            const int s = sb + u;
            v2f lv[4];
            const bool have_next = (s + 1 < D_DIM);
            if (have_next) fetch_slice(s + 1, lv);
            if (wactive) wconv(u & 1);
            if (have_next) commit_slice((u + 1) & 1, lv);
            __syncthreads();
            if (hworker) {
                // H-conv, 2 outputs from 12 b128 reads
                v2f z0x = {0.f,0.f}, z0q = {0.f,0.f};
                v2f z1x = {0.f,0.f}, z1q = {0.f,0.f};
#pragma unroll
                for (int t = 0; t < 12; ++t) {
                    const float4 m = mid[u & 1][hb + t][hw];
                    const v2f ma = {m.x, m.y};
                    const v2f mb = {m.z, m.w};
                    if (t <= 10) {
                        const v2f g2 = {gwp.g[t], gwp.g[t]};
                        z0x = __builtin_elementwise_fma(g2, ma, z0x);
                        z0q = __builtin_elementwise_fma(g2, mb, z0q);
                    }
                    if (t >= 1) {
                        const v2f g2 = {gwp.g[t-1], gwp.g[t-1]};
                        z1x = __builtin_elementwise_fma(g2, ma, z1x);
                        z1q = __builtin_elementwise_fma(g2, mb, z1q);
                    }
                }
                w0xy[10 + u] = z0x; w0qp[10 + u] = z0q;
                w1xy[10 + u] = z1x; w1qp[10 + u] = z1q;
                if (s >= HALO) {   // output d = s-5
                    v2f mx0 = {0.f,0.f}, mq0 = {0.f,0.f};
                    v2f mx1 = {0.f,0.f}, mq1 = {0.f,0.f};
#pragma unroll
                    for (int t = 0; t < 11; ++t) {
                        const v2f g2 = {gwp.g[t], gwp.g[t]};
                        mx0 = __builtin_elementwise_fma(g2, w0xy[u + t], mx0);
                        mq0 = __builtin_elementwise_fma(g2, w0qp[u + t], mq0);
                        mx1 = __builtin_elementwise_fma(g2, w1xy[u + t], mx1);
                        mq1 = __builtin_elementwise_fma(g2, w1qp[u + t], mq1);
                    }
                    ssim_add(mx0, mq0);
                    ssim_add(mx1, mq1);
                }
            }
        }
        if (hworker) {
            // shift both windows by 4
#pragma unroll
            for (int k = 0; k < 10; ++k) {
                w0xy[k] = w0xy[k + 4]; w0qp[k] = w0qp[k + 4];
                w1xy[k] = w1xy[k + 4]; w1qp[k] = w1qp[k + 4];
            }
        }
    }

    // epilogue: outputs d = 59..63; windows hold slices 54+k at slot k (0..9)
    if (hworker) {
#pragma unroll
        for (int i = 10; i < 14; ++i) {
            w0xy[i] = (v2f){0.f, 0.f}; w0qp[i] = (v2f){0.f, 0.f};
            w1xy[i] = (v2f){0.f, 0.f}; w1qp[i] = (v2f){0.f, 0.f};
        }
#pragma unroll
        for (int u2 = 0; u2 < 5; ++u2) {   // output d = 59 + u2
            v2f mx0 = {0.f,0.f}, mq0 = {0.f,0.f};
            v2f mx1 = {0.f,0.f}, mq1 = {0.f,0.f};
#pragma unroll
            for (int t = 0; t < 11; ++t) {
                if (u2 + t <= 13) {        // static guard; dropped taps zero
                    const v2f g2 = {gwp.g[t], gwp.g[t]};
                    mx0 = __builtin_elementwise_fma(g2, w0xy[u2 + t], mx0);
                    mq0 = __builtin_elementwise_fma(g2, w0qp[u2 + t], mq0);
                    mx1 = __builtin_elementwise_fma(g2, w1xy[u2 + t], mx1);
                    mq1 = __builtin_elementwise_fma(g2, w1qp[u2 + t], mq1);
                }
            }
            ssim_add(mx0, mq0);
            ssim_add(mx1, mq1);
        }
    }

    // ---- block reduction -> one partial per block ----
#pragma unroll
    for (int off = 32; off > 0; off >>= 1) accum += __shfl_down(accum, off, 64);
    const int wave = tid >> 6;
    const int lane = tid & 63;
    if (lane == 0) rbuf[wave] = accum;
    __syncthreads();
    if (tid == 0) partial[bid] = rbuf[0] + rbuf[1] + rbuf[2] + rbuf[3];
}

extern "C" void kernel_launch(void* const* d_in, const int* in_sizes, int n_in,
                              void* d_out, int out_size, void* d_ws, size_t ws_size,
                              hipStream_t stream) {
    const float* img1 = (const float*)d_in[0];
    const float* img2 = (const float*)d_in[1];
    float* out = (float*)d_out;
    float* partial = (float*)d_ws;   // NBLOCKS floats

    GW gw;
    {
        double gd[11];
        double ssum = 0.0;
        for (int i = 0; i < 11; ++i) {
            const double t = (double)(i - 5);
            gd[i] = exp(-(t * t) / 4.5);
            ssum += gd[i];
        }
        for (int i = 0; i < 11; ++i) gw.g[i] = (float)(gd[i] / ssum);
    }

    ssim3d_kernel<<<NBLOCKS, 256, 0, stream>>>(img1, img2, partial, gw);
    finalize_kernel<<<1, 256, 0, stream>>>(partial, out);
}